// Round 6
// baseline (837.100 us; speedup 1.0000x reference)
//
#include <hip/hip_runtime.h>
#include <math.h>

#define N_RES 8192
#define N_IN  128
#define BATCH 16
#define LEAK  0.9f

#define NRB  32        // row buckets (256 rows each)
#define RPB  256
#define NCB  33        // col buckets (256 cols; cb=32 holds input cols 8192..8319)
#define NT   (NRB * NCB)          // 1056 tiles
#define CAP1 229376    // per row-bucket capacity (avg 213K, +35 sigma)
#define CAPT 7424      // per tile capacity (avg 6553, +10.7 sigma)
#define EPB  4096      // entries per scatter block
#define SB2  ((CAP1 + EPB - 1) / EPB)   // 56 chunks per row bucket in pass 2

// ws layout (bytes):
//   srcT     @ 0      : [8320][16] f32 transposed state|x   (532,480)
//   cursors  @ 1 MiB  : int gcur1[32], gcur2[1056]          (4,352)
//   partials @ 2 MiB  : [NT][RPB][BATCH] f32                (17,301,504)
//   e1       @ 20 MiB : uint2[NRB][CAP1]                    (58,720,256)
//   e2       @ 76 MiB : uint2[NT][CAPT]                     (62,717,952)
#define OFF_SRCT 0
#define OFF_CURS (1u << 20)
#define OFF_PART (2u << 20)
#define OFF_E1   (20u << 20)
#define OFF_E2   (76u << 20)
#define REQ_TIER_A ((size_t)OFF_E2 + (size_t)NT * CAPT * 8)   // ~135.8 MiB
#define REQ_TIER_B ((size_t)OFF_E1 + (size_t)NRB * CAP1 * 8)  // ~76 MiB (R5 path)

#define B_K2 32        // Tier-B phase-2 blocks per bucket
#define B_EPT 16       // Tier-B scatter entries/thread

// ---------------------------------------------------------------------------
__global__ __launch_bounds__(256) void transpose_kernel(
    const float* __restrict__ state,  // [BATCH][N_RES]
    const float* __restrict__ x,      // [BATCH][N_IN]
    float* __restrict__ srcT) {       // [8320][BATCH]
  int tid = blockIdx.x * 256 + threadIdx.x;
  if (tid < N_RES * BATCH) {
    int b = tid >> 13;
    int r = tid & (N_RES - 1);
    srcT[r * BATCH + b] = state[tid];
  }
  if (tid < N_IN * BATCH) {
    int b = tid >> 7;
    int c = tid & (N_IN - 1);
    srcT[(N_RES + c) * BATCH + b] = x[tid];
  }
}

// ---------------------------------------------------------------------------
// Tier A pass 1: bin COO entries by row bucket. LDS-reorder so global writes
// are coalesced (~1 KB clumps per bin per block).
__global__ __launch_bounds__(256) void scatter_rows(
    const float* __restrict__ vals,
    const int* __restrict__ rows,
    const int* __restrict__ cols,
    int nnz, int col_off,
    uint2* __restrict__ e1,          // [NRB][CAP1]
    int* __restrict__ gcur1) {       // [NRB]
  __shared__ int hist[NRB];
  __shared__ int lbase[NRB];
  __shared__ int gbase[NRB];
  __shared__ uint2 stg[EPB];          // 32 KB
  __shared__ unsigned char binof[EPB];// 4 KB
  int tid = threadIdx.x;
  if (tid < NRB) hist[tid] = 0;
  __syncthreads();

  int base = blockIdx.x * EPB;
  int n = nnz - base;
  if (n > EPB) n = EPB;

  uint2 ent[16];
  int bb[16], lp[16];
#pragma unroll
  for (int e = 0; e < 16; ++e) {
    int i = e * 256 + tid;
    bb[e] = -1;
    if (i < n) {
      int r = rows[base + i];
      int c = cols[base + i] + col_off;
      float v = vals[base + i];
      bb[e] = r >> 8;
      ent[e] = make_uint2(__float_as_uint(v),
                          ((unsigned)(r & 255) << 14) | (unsigned)c);
      lp[e] = atomicAdd(&hist[bb[e]], 1);
    }
  }
  __syncthreads();
  if (tid == 0) {
    int acc = 0;
    for (int b = 0; b < NRB; ++b) { lbase[b] = acc; acc += hist[b]; }
  }
  __syncthreads();
  if (tid < NRB) gbase[tid] = hist[tid] ? atomicAdd(&gcur1[tid], hist[tid]) : 0;
#pragma unroll
  for (int e = 0; e < 16; ++e) {
    if (bb[e] >= 0) {
      int p = lbase[bb[e]] + lp[e];
      stg[p] = ent[e];
      binof[p] = (unsigned char)bb[e];
    }
  }
  __syncthreads();
  for (int i = tid; i < n; i += 256) {
    int b = binof[i];
    int p = gbase[b] + (i - lbase[b]);
    if (p < CAP1) e1[(size_t)b * CAP1 + p] = stg[i];
  }
}

// ---------------------------------------------------------------------------
// Tier A pass 2: bin each row-bucket segment by col bucket -> (rb,cb) tiles.
__global__ __launch_bounds__(256) void scatter_cols(
    const uint2* __restrict__ e1,
    const int* __restrict__ gcur1,
    uint2* __restrict__ e2,          // [NT][CAPT]
    int* __restrict__ gcur2) {       // [NT]
  int rb = blockIdx.x / SB2;
  int ch = blockIdx.x - rb * SB2;
  int cnt = gcur1[rb];
  if (cnt > CAP1) cnt = CAP1;
  int base = ch * EPB;
  if (base >= cnt) return;           // uniform exit, before any barrier use
  int n = cnt - base;
  if (n > EPB) n = EPB;

  __shared__ int hist[NCB];
  __shared__ int lbase[NCB];
  __shared__ int gbase[NCB];
  __shared__ uint2 stg[EPB];
  __shared__ unsigned char binof[EPB];
  int tid = threadIdx.x;
  if (tid < NCB) hist[tid] = 0;
  __syncthreads();

  const uint2* __restrict__ src = e1 + (size_t)rb * CAP1 + base;
  uint2 ent[16];
  int bb[16], lp[16];
#pragma unroll
  for (int e = 0; e < 16; ++e) {
    int i = e * 256 + tid;
    bb[e] = -1;
    if (i < n) {
      ent[e] = src[i];
      bb[e] = (int)((ent[e].y & 16383u) >> 8);   // col bucket
      lp[e] = atomicAdd(&hist[bb[e]], 1);
    }
  }
  __syncthreads();
  if (tid == 0) {
    int acc = 0;
    for (int b = 0; b < NCB; ++b) { lbase[b] = acc; acc += hist[b]; }
  }
  __syncthreads();
  if (tid < NCB)
    gbase[tid] = hist[tid] ? atomicAdd(&gcur2[rb * NCB + tid], hist[tid]) : 0;
#pragma unroll
  for (int e = 0; e < 16; ++e) {
    if (bb[e] >= 0) {
      int p = lbase[bb[e]] + lp[e];
      stg[p] = ent[e];
      binof[p] = (unsigned char)bb[e];
    }
  }
  __syncthreads();
  for (int i = tid; i < n; i += 256) {
    int b = binof[i];
    int p = gbase[b] + (i - lbase[b]);
    if (p < CAPT)
      e2[(size_t)(rb * NCB + b) * CAPT + p] = stg[i];
  }
}

// ---------------------------------------------------------------------------
// Tier A phase 2: one block per (rb,cb) tile. srcT col-slice (16 KB) and the
// row tile (16 KB) both live in LDS -> zero scattered global accesses.
// Entry stream is coalesced wave loads with register double-buffer (R4/R5
// proven structure).
__global__ __launch_bounds__(256) void accum_tiled(
    const uint2* __restrict__ e2,
    const int* __restrict__ gcur2,
    const float* __restrict__ srcT,     // [8320][16]
    float* __restrict__ partials) {     // [NT][RPB][BATCH]
  int t = blockIdx.x;
  int rb = t / NCB;
  int cb = t - rb * NCB;
  (void)rb;
  __shared__ float tile[RPB * BATCH];   // 16 KB
  __shared__ float slice[256 * BATCH];  // 16 KB
  __shared__ uint2 stage[4][64];        // 2 KB
  int tid = threadIdx.x;

  // Load srcT slice for cols [cb*256, cb*256+255] (cb=32 has only 128 rows).
  const float4* __restrict__ s4 = (const float4*)srcT;
  float4* __restrict__ sl4 = (float4*)slice;
#pragma unroll
  for (int j = 0; j < 4; ++j) {
    int idx = j * 256 + tid;            // float4 index within slice [0,1024)
    int gidx = cb * 1024 + idx;         // srcT has 8320*4 = 33280 float4s
    sl4[idx] = (gidx < 33280) ? s4[gidx] : make_float4(0.f, 0.f, 0.f, 0.f);
  }
#pragma unroll
  for (int i = tid; i < RPB * BATCH; i += 256) tile[i] = 0.0f;
  __syncthreads();

  int count = gcur2[t];
  if (count > CAPT) count = CAPT;
  const uint2* __restrict__ eb = e2 + (size_t)t * CAPT;
  int wave = tid >> 6, lane = tid & 63;
  int g = lane >> 4, lb = lane & 15;
  uint2* __restrict__ st = stage[wave];

  int bpos = wave * 64;
  uint2 cur = make_uint2(0u, 0u);       // zero entry: +0 to row 0 (harmless)
  if (bpos + lane < count) cur = eb[bpos + lane];

  for (; bpos < count; bpos += 256) {
    int nb = bpos + 256;
    uint2 nxt = make_uint2(0u, 0u);
    if (nb + lane < count) nxt = eb[nb + lane];

    st[lane] = cur;                     // wave-private staging
#pragma unroll
    for (int j = 0; j < 16; ++j) {
      int jj = (j + g * 4) & 15;        // bank rotation across groups
      uint2 eld = st[g * 16 + jj];
      float vv = __uint_as_float(eld.x);
      int lcol = (int)(eld.y & 255u);
      int rl   = (int)(eld.y >> 14);
      float s = slice[lcol * 16 + lb];  // LDS, not global
      unsafeAtomicAdd(&tile[rl * 16 + lb], vv * s);
    }
    cur = nxt;
  }
  __syncthreads();

  float* __restrict__ pb = partials + (size_t)t * (RPB * BATCH);
#pragma unroll
  for (int i = tid; i < RPB * BATCH; i += 256) pb[i] = tile[i];
}

// ---------------------------------------------------------------------------
__global__ __launch_bounds__(256) void finalize_tiled(
    const float* __restrict__ partials,  // [NT][RPB][BATCH]
    const float* __restrict__ state,     // [BATCH][N_RES]
    const float* __restrict__ res_bias,
    const float* __restrict__ in_bias,
    float* __restrict__ out) {           // [BATCH][N_RES]
  int tid = blockIdx.x * 256 + threadIdx.x;
  if (tid >= N_RES * BATCH) return;
  int b = tid & 15;
  int r = tid >> 4;
  int rb = r >> 8, rl = r & 255;
  const float* __restrict__ p =
      partials + (size_t)rb * NCB * (RPB * BATCH) + rl * 16 + b;
  float z = 0.0f;
#pragma unroll
  for (int cb = 0; cb < NCB; ++cb) z += p[(size_t)cb * (RPB * BATCH)];
  z += res_bias[r] + in_bias[r];
  int idx = b * N_RES + r;
  out[idx] = (1.0f - LEAK) * state[idx] + LEAK * erff(z);
}

// ===========================================================================
// Tier B: Round-5 path (row buckets only), needs ~76 MiB ws.
// ===========================================================================
__global__ __launch_bounds__(256) void scatter_kernel_b(
    const float* __restrict__ vals,
    const int* __restrict__ rows,
    const int* __restrict__ cols,
    int nnz, int col_off,
    uint2* __restrict__ entries,      // [NRB][CAP1]
    int* __restrict__ cursors) {      // [NRB]
  __shared__ int lcount[NRB];
  __shared__ int lbase[NRB];
  int tid = threadIdx.x;
  if (tid < NRB) lcount[tid] = 0;
  __syncthreads();
  int base = blockIdx.x * (256 * B_EPT);
  float v[B_EPT];
  unsigned a[B_EPT];
  int bk[B_EPT];
#pragma unroll
  for (int e = 0; e < B_EPT; ++e) {
    int i = base + e * 256 + tid;
    bk[e] = -1;
    if (i < nnz) {
      int r = rows[i];
      int c = cols[i];
      v[e] = vals[i];
      bk[e] = r >> 8;
      a[e] = ((unsigned)(r & 255) << 14) | (unsigned)(c + col_off);
      atomicAdd(&lcount[bk[e]], 1);
    }
  }
  __syncthreads();
  if (tid < NRB) {
    int c = lcount[tid];
    lbase[tid] = (c > 0) ? atomicAdd(&cursors[tid], c) : 0;
    lcount[tid] = 0;
  }
  __syncthreads();
#pragma unroll
  for (int e = 0; e < B_EPT; ++e) {
    if (bk[e] >= 0) {
      int pos = lbase[bk[e]] + atomicAdd(&lcount[bk[e]], 1);
      if (pos < CAP1)
        entries[(size_t)bk[e] * CAP1 + pos] = make_uint2(__float_as_uint(v[e]), a[e]);
    }
  }
}

__global__ __launch_bounds__(256) void accum_kernel_b(
    const uint2* __restrict__ entries,
    const int* __restrict__ cursors,
    const float* __restrict__ srcT,
    float* __restrict__ partials) {     // [NRB][B_K2][RPB][BATCH]
  int bucket = blockIdx.x / B_K2;
  int k = blockIdx.x - bucket * B_K2;
  __shared__ float tile[RPB * BATCH];
  __shared__ uint2 stage[4][64];
  int tid = threadIdx.x;
#pragma unroll
  for (int i = tid; i < RPB * BATCH; i += 256) tile[i] = 0.0f;
  __syncthreads();
  int count = cursors[bucket];
  if (count > CAP1) count = CAP1;
  int start = (int)((long long)count * k / B_K2);
  int end   = (int)((long long)count * (k + 1) / B_K2);
  const uint2* __restrict__ eb = entries + (size_t)bucket * CAP1;
  int wave = tid >> 6, lane = tid & 63, g = lane >> 4, lb = lane & 15;
  uint2* __restrict__ st = stage[wave];
  int base = start + wave * 64;
  uint2 cur = make_uint2(0u, 0u);
  if (base + lane < end) cur = eb[base + lane];
  for (; base < end; base += 256) {
    int nbase = base + 256;
    uint2 nxt = make_uint2(0u, 0u);
    if (nbase + lane < end) nxt = eb[nbase + lane];
    st[lane] = cur;
#pragma unroll
    for (int j = 0; j < 16; ++j) {
      int jj = (j + g * 4) & 15;
      uint2 eld = st[g * 16 + jj];
      float vv = __uint_as_float(eld.x);
      int col = (int)(eld.y & 16383u);
      int rl  = (int)(eld.y >> 14);
      float s = srcT[col * BATCH + lb];
      unsafeAtomicAdd(&tile[rl * BATCH + lb], vv * s);
    }
    cur = nxt;
  }
  __syncthreads();
  float* __restrict__ pb = partials + ((size_t)bucket * B_K2 + k) * (RPB * BATCH);
#pragma unroll
  for (int i = tid; i < RPB * BATCH; i += 256) pb[i] = tile[i];
}

__global__ __launch_bounds__(256) void finalize_kernel_b(
    const float* __restrict__ partials,
    const float* __restrict__ state,
    const float* __restrict__ res_bias,
    const float* __restrict__ in_bias,
    float* __restrict__ out) {
  int tid = blockIdx.x * 256 + threadIdx.x;
  if (tid >= N_RES * BATCH) return;
  int b = tid & 15;
  int r = tid >> 4;
  int bucket = r >> 8;
  int rl = r & 255;
  const float* __restrict__ p =
      partials + (size_t)bucket * B_K2 * (RPB * BATCH) + rl * BATCH + b;
  float z = 0.0f;
#pragma unroll
  for (int k = 0; k < B_K2; ++k) z += p[(size_t)k * (RPB * BATCH)];
  z += res_bias[r] + in_bias[r];
  int idx = b * N_RES + r;
  out[idx] = (1.0f - LEAK) * state[idx] + LEAK * erff(z);
}

// Tier C: pure atomic fallback.
__global__ __launch_bounds__(256) void spmm_atomic(
    const float* __restrict__ vals,
    const int* __restrict__ rows,
    const int* __restrict__ cols,
    const float* __restrict__ srcT, int col_off,
    float* __restrict__ z, int nnz) {
  int i = blockIdx.x * blockDim.x + threadIdx.x;
  if (i >= nnz) return;
  float v = vals[i];
  int r = rows[i];
  int c = cols[i] + col_off;
  const float4* __restrict__ sp = (const float4*)(srcT + c * BATCH);
  float* zr = z + r * BATCH;
#pragma unroll
  for (int q = 0; q < 4; ++q) {
    float4 s = sp[q];
    unsafeAtomicAdd(zr + q * 4 + 0, v * s.x);
    unsafeAtomicAdd(zr + q * 4 + 1, v * s.y);
    unsafeAtomicAdd(zr + q * 4 + 2, v * s.z);
    unsafeAtomicAdd(zr + q * 4 + 3, v * s.w);
  }
}

__global__ __launch_bounds__(256) void finalize_z_kernel(
    const float* __restrict__ z,
    const float* __restrict__ state,
    const float* __restrict__ res_bias,
    const float* __restrict__ in_bias,
    float* __restrict__ out) {
  int tid = blockIdx.x * 256 + threadIdx.x;
  if (tid >= BATCH * N_RES) return;
  int b = tid >> 13;
  int r = tid & (N_RES - 1);
  float zz = z[r * BATCH + b] + res_bias[r] + in_bias[r];
  out[tid] = (1.0f - LEAK) * state[tid] + LEAK * erff(zz);
}

// ---------------------------------------------------------------------------
extern "C" void kernel_launch(void* const* d_in, const int* in_sizes, int n_in,
                              void* d_out, int out_size, void* d_ws, size_t ws_size,
                              hipStream_t stream) {
  const float* state    = (const float*)d_in[0];
  const float* x        = (const float*)d_in[1];
  const float* res_vals = (const float*)d_in[2];
  const int*   res_rows = (const int*)d_in[3];
  const int*   res_cols = (const int*)d_in[4];
  const float* res_bias = (const float*)d_in[5];
  const float* in_vals  = (const float*)d_in[6];
  const int*   in_rows  = (const int*)d_in[7];
  const int*   in_cols  = (const int*)d_in[8];
  const float* in_bias  = (const float*)d_in[9];

  const int res_nnz = in_sizes[2];
  const int in_nnz  = in_sizes[6];

  char* ws = (char*)d_ws;
  float* srcT = (float*)(ws + OFF_SRCT);
  float* out = (float*)d_out;

  if (ws_size >= REQ_TIER_A) {
    int* gcur1 = (int*)(ws + OFF_CURS);
    int* gcur2 = gcur1 + NRB;
    float* partials = (float*)(ws + OFF_PART);
    uint2* e1 = (uint2*)(ws + OFF_E1);
    uint2* e2 = (uint2*)(ws + OFF_E2);

    hipMemsetAsync(gcur1, 0, (NRB + NT) * sizeof(int), stream);
    transpose_kernel<<<(N_RES * BATCH + 255) / 256, 256, 0, stream>>>(state, x, srcT);

    scatter_rows<<<(res_nnz + EPB - 1) / EPB, 256, 0, stream>>>(
        res_vals, res_rows, res_cols, res_nnz, 0, e1, gcur1);
    scatter_rows<<<(in_nnz + EPB - 1) / EPB, 256, 0, stream>>>(
        in_vals, in_rows, in_cols, in_nnz, N_RES, e1, gcur1);

    scatter_cols<<<NRB * SB2, 256, 0, stream>>>(e1, gcur1, e2, gcur2);

    accum_tiled<<<NT, 256, 0, stream>>>(e2, gcur2, srcT, partials);

    finalize_tiled<<<(N_RES * BATCH + 255) / 256, 256, 0, stream>>>(
        partials, state, res_bias, in_bias, out);
  } else if (ws_size >= REQ_TIER_B) {
    int* cursors = (int*)(ws + OFF_CURS);
    float* partials = (float*)(ws + OFF_PART);
    uint2* entries = (uint2*)(ws + OFF_E1);

    hipMemsetAsync(cursors, 0, NRB * sizeof(int), stream);
    transpose_kernel<<<(N_RES * BATCH + 255) / 256, 256, 0, stream>>>(state, x, srcT);
    scatter_kernel_b<<<(res_nnz + 256 * B_EPT - 1) / (256 * B_EPT), 256, 0, stream>>>(
        res_vals, res_rows, res_cols, res_nnz, 0, entries, cursors);
    scatter_kernel_b<<<(in_nnz + 256 * B_EPT - 1) / (256 * B_EPT), 256, 0, stream>>>(
        in_vals, in_rows, in_cols, in_nnz, N_RES, entries, cursors);
    accum_kernel_b<<<NRB * B_K2, 256, 0, stream>>>(entries, cursors, srcT, partials);
    finalize_kernel_b<<<(N_RES * BATCH + 255) / 256, 256, 0, stream>>>(
        partials, state, res_bias, in_bias, out);
  } else {
    float* z = (float*)(ws + OFF_CURS);
    hipMemsetAsync(z, 0, N_RES * BATCH * sizeof(float), stream);
    transpose_kernel<<<(N_RES * BATCH + 255) / 256, 256, 0, stream>>>(state, x, srcT);
    spmm_atomic<<<(res_nnz + 255) / 256, 256, 0, stream>>>(
        res_vals, res_rows, res_cols, srcT, 0, z, res_nnz);
    spmm_atomic<<<(in_nnz + 255) / 256, 256, 0, stream>>>(
        in_vals, in_rows, in_cols, srcT, N_RES, z, in_nnz);
    finalize_z_kernel<<<(BATCH * N_RES + 255) / 256, 256, 0, stream>>>(
        z, state, res_bias, in_bias, out);
  }
}

// Round 7
// 261.025 us; speedup vs baseline: 3.2070x; 3.2070x over previous
//
#include <hip/hip_runtime.h>
#include <math.h>

#define N_RES 8192
#define N_IN  128
#define BATCH 16
#define LEAK  0.9f

#define NBK   256      // pass-1 buckets (row>>5), 32 rows each
#define CAP1B 28672    // per-bucket capacity (avg 26.6K, +12 sigma)
#define CHUNK 4096     // entries per binning block
#define SB2   (CAP1B / CHUNK)   // 7 chunks per bucket in pass 2
#define CAPR  1024     // per-row CSR slot capacity (avg 832, +6.6 sigma)

// ws layout (bytes):
//   srcT    @ 0        : [8320][16] f32 transposed state|x  (532,480)
//   row_cur @ 1 MiB    : int[8192]                          (32,768)
//   bcur    @ 1MiB+32K : int[256]                           (1,024)
//   z       @ 1MiB+64K : [8192][16] f32                     (524,288)
//   e1      @ 2 MiB    : uint2[256][28672]                  (58,720,256)
//   e2      @ 64 MiB   : uint2[8192][1024]                  (67,108,864)
#define OFF_SRCT 0
#define OFF_RCUR (1u << 20)
#define OFF_BCUR ((1u << 20) + 32768u)
#define OFF_Z    ((1u << 20) + 65536u)
#define OFF_E1   (2u << 20)
#define OFF_E2   (64u << 20)
#define REQ_A    ((size_t)OFF_E2 + (size_t)N_RES * CAPR * 8)   // 128 MiB

// ---------------------------------------------------------------------------
__global__ __launch_bounds__(256) void transpose_kernel(
    const float* __restrict__ state,  // [BATCH][N_RES]
    const float* __restrict__ x,      // [BATCH][N_IN]
    float* __restrict__ srcT) {       // [8320][BATCH]
  int tid = blockIdx.x * 256 + threadIdx.x;
  if (tid < N_RES * BATCH) {
    int b = tid >> 13;
    int r = tid & (N_RES - 1);
    srcT[r * BATCH + b] = state[tid];
  }
  if (tid < N_IN * BATCH) {
    int b = tid >> 7;
    int c = tid & (N_IN - 1);
    srcT[(N_RES + c) * BATCH + b] = x[tid];
  }
}

// ---------------------------------------------------------------------------
// Pass 1: bin by row>>5 (256 buckets). LDS reorder -> coalesced bin writes.
__global__ __launch_bounds__(256) void pass1_bin(
    const float* __restrict__ vals,
    const int* __restrict__ rows,
    const int* __restrict__ cols,
    int nnz, int col_off,
    uint2* __restrict__ e1,          // [NBK][CAP1B]
    int* __restrict__ bcur) {        // [NBK]
  __shared__ int hist[NBK];
  __shared__ int lbase[NBK];
  __shared__ int gbase[NBK];
  __shared__ uint2 stg[CHUNK];          // 32 KB
  __shared__ unsigned char binof[CHUNK];
  int tid = threadIdx.x;
  hist[tid] = 0;                        // 256 threads == NBK bins
  __syncthreads();

  int base = blockIdx.x * CHUNK;
  int n = nnz - base;
  if (n > CHUNK) n = CHUNK;

  uint2 ent[16];
  int bb[16], lp[16];
#pragma unroll
  for (int e = 0; e < 16; ++e) {
    int i = e * 256 + tid;
    bb[e] = -1;
    if (i < n) {
      int r = rows[base + i];
      int c = cols[base + i] + col_off;
      float v = vals[base + i];
      bb[e] = r >> 5;
      ent[e] = make_uint2(__float_as_uint(v),
                          ((unsigned)(r & 31) << 14) | (unsigned)c);
      lp[e] = atomicAdd(&hist[bb[e]], 1);
    }
  }
  __syncthreads();
  if (tid == 0) {
    int acc = 0;
    for (int b = 0; b < NBK; ++b) { lbase[b] = acc; acc += hist[b]; }
  }
  __syncthreads();
  gbase[tid] = hist[tid] ? atomicAdd(&bcur[tid], hist[tid]) : 0;
#pragma unroll
  for (int e = 0; e < 16; ++e) {
    if (bb[e] >= 0) {
      int p = lbase[bb[e]] + lp[e];
      stg[p] = ent[e];
      binof[p] = (unsigned char)bb[e];
    }
  }
  __syncthreads();
  for (int i = tid; i < n; i += 256) {
    int b = binof[i];
    int p = gbase[b] + (i - lbase[b]);
    if (p < CAP1B) e1[(size_t)b * CAP1B + p] = stg[i];
  }
}

// ---------------------------------------------------------------------------
// Pass 2: per-bucket sort by exact row (32 bins) into per-row CSR slots.
__global__ __launch_bounds__(256) void pass2_sort(
    const uint2* __restrict__ e1,
    const int* __restrict__ bcur,
    uint2* __restrict__ e2,          // [N_RES][CAPR]
    int* __restrict__ rcur) {        // [N_RES]
  int bucket = blockIdx.x / SB2;
  int ch = blockIdx.x - bucket * SB2;
  int cnt = bcur[bucket];
  if (cnt > CAP1B) cnt = CAP1B;
  int base = ch * CHUNK;
  if (base >= cnt) return;            // uniform exit before any barrier
  int n = cnt - base;
  if (n > CHUNK) n = CHUNK;

  __shared__ int hist[32];
  __shared__ int lbase[32];
  __shared__ int gbase[32];
  __shared__ uint2 stg[CHUNK];
  __shared__ unsigned char binof[CHUNK];
  int tid = threadIdx.x;
  if (tid < 32) hist[tid] = 0;
  __syncthreads();

  const uint2* __restrict__ src = e1 + (size_t)bucket * CAP1B + base;
  uint2 ent[16];
  int bb[16], lp[16];
#pragma unroll
  for (int e = 0; e < 16; ++e) {
    int i = e * 256 + tid;
    bb[e] = -1;
    if (i < n) {
      ent[e] = src[i];
      bb[e] = (int)(ent[e].y >> 14);        // local row 0..31
      lp[e] = atomicAdd(&hist[bb[e]], 1);
    }
  }
  __syncthreads();
  if (tid == 0) {
    int acc = 0;
    for (int b = 0; b < 32; ++b) { lbase[b] = acc; acc += hist[b]; }
  }
  __syncthreads();
  if (tid < 32)
    gbase[tid] = hist[tid] ? atomicAdd(&rcur[bucket * 32 + tid], hist[tid]) : 0;
#pragma unroll
  for (int e = 0; e < 16; ++e) {
    if (bb[e] >= 0) {
      int p = lbase[bb[e]] + lp[e];
      stg[p] = ent[e];
      binof[p] = (unsigned char)bb[e];
    }
  }
  __syncthreads();
  for (int i = tid; i < n; i += 256) {
    int b = binof[i];
    int p = gbase[b] + (i - lbase[b]);
    if (p < CAPR)
      e2[(size_t)(bucket * 32 + b) * CAPR + p] = stg[i];
  }
}

// ---------------------------------------------------------------------------
// Pad each row's CSR slot to a multiple of 64 with zero entries.
__global__ __launch_bounds__(256) void tail_zero(
    uint2* __restrict__ e2, const int* __restrict__ rcur) {
  int gid = blockIdx.x * 256 + threadIdx.x;
  int r = gid >> 6;
  int lane = gid & 63;
  if (r >= N_RES) return;
  int cnt = rcur[r];
  if (cnt > CAPR) cnt = CAPR;
  int rup = (cnt + 63) & ~63;         // cnt <= 1024 -> rup <= CAPR
  int idx = cnt + lane;
  if (idx < rup) e2[(size_t)r * CAPR + idx] = make_uint2(0u, 0u);
}

// ---------------------------------------------------------------------------
// One wave per row, ZERO atomics: 4 quarters x 16 batch-lanes, 4 VGPR
// accumulators, coalesced 512B entry loads with register double-buffer,
// wave-private LDS staging, bank-rotated broadcast reads, srcT gathers from
// L2, cross-quarter shfl reduce, one 64B z store.
__global__ __launch_bounds__(256) void accum_csr(
    const uint2* __restrict__ e2,
    const int* __restrict__ rcur,
    const float* __restrict__ srcT,     // [8320][16]
    float* __restrict__ z) {            // [N_RES][16]
  __shared__ uint2 stg[4][64];          // wave-private, 2 KB
  int tid = threadIdx.x;
  int wave = tid >> 6, lane = tid & 63;
  int q = lane >> 4, lb = lane & 15;
  int r = blockIdx.x * 4 + wave;        // 2048 blocks -> r in [0, 8192)

  int cnt = rcur[r];
  if (cnt > CAPR) cnt = CAPR;
  int rup = (cnt + 63) & ~63;
  const uint2* __restrict__ eb = e2 + (size_t)r * CAPR;
  uint2* __restrict__ st = stg[wave];

  float a0 = 0.f, a1 = 0.f, a2 = 0.f, a3 = 0.f;
  uint2 cur = make_uint2(0u, 0u);
  if (rup > 0) cur = eb[lane];

  for (int i = 0; i < rup; i += 64) {
    uint2 nxt = make_uint2(0u, 0u);
    if (i + 64 < rup) nxt = eb[i + 64 + lane];   // prefetch next batch

    st[lane] = cur;                     // same-wave LDS: in-order, no barrier
#pragma unroll
    for (int k = 0; k < 16; ++k) {
      int kk = (k + 4 * q) & 15;        // bank rotation across quarters
      uint2 ee = st[q * 16 + kk];       // broadcast within quarter
      float v = __uint_as_float(ee.x);
      int c = (int)(ee.y & 16383u);
      float s = srcT[c * 16 + lb];      // one 64B line per quarter, L2-hot
      float p = v * s;
      if ((k & 3) == 0) a0 += p;
      else if ((k & 3) == 1) a1 += p;
      else if ((k & 3) == 2) a2 += p;
      else a3 += p;
    }
    cur = nxt;
  }
  float sum = (a0 + a1) + (a2 + a3);
  sum += __shfl_xor(sum, 16);           // combine quarters
  sum += __shfl_xor(sum, 32);
  if (lane < 16) z[r * 16 + lane] = sum;
}

// ---------------------------------------------------------------------------
__global__ __launch_bounds__(256) void finalize_csr(
    const float* __restrict__ z,        // [N_RES][16]
    const float* __restrict__ state,    // [BATCH][N_RES]
    const float* __restrict__ res_bias,
    const float* __restrict__ in_bias,
    float* __restrict__ out) {          // [BATCH][N_RES]
  int tid = blockIdx.x * 256 + threadIdx.x;
  if (tid >= N_RES * BATCH) return;
  int b = tid >> 13;
  int r = tid & (N_RES - 1);
  float zz = z[r * 16 + b] + res_bias[r] + in_bias[r];
  out[tid] = (1.0f - LEAK) * state[tid] + LEAK * erff(zz);
}

// ---------------------------------------------------------------------------
// Fallback (small ws): atomic path, correct but slow.
__global__ __launch_bounds__(256) void spmm_atomic(
    const float* __restrict__ vals,
    const int* __restrict__ rows,
    const int* __restrict__ cols,
    const float* __restrict__ srcT, int col_off,
    float* __restrict__ zz, int nnz) {
  int i = blockIdx.x * blockDim.x + threadIdx.x;
  if (i >= nnz) return;
  float v = vals[i];
  int r = rows[i];
  int c = cols[i] + col_off;
  const float4* __restrict__ sp = (const float4*)(srcT + c * BATCH);
  float* zr = zz + r * BATCH;
#pragma unroll
  for (int qq = 0; qq < 4; ++qq) {
    float4 s = sp[qq];
    unsafeAtomicAdd(zr + qq * 4 + 0, v * s.x);
    unsafeAtomicAdd(zr + qq * 4 + 1, v * s.y);
    unsafeAtomicAdd(zr + qq * 4 + 2, v * s.z);
    unsafeAtomicAdd(zr + qq * 4 + 3, v * s.w);
  }
}

// ---------------------------------------------------------------------------
extern "C" void kernel_launch(void* const* d_in, const int* in_sizes, int n_in,
                              void* d_out, int out_size, void* d_ws, size_t ws_size,
                              hipStream_t stream) {
  const float* state    = (const float*)d_in[0];
  const float* x        = (const float*)d_in[1];
  const float* res_vals = (const float*)d_in[2];
  const int*   res_rows = (const int*)d_in[3];
  const int*   res_cols = (const int*)d_in[4];
  const float* res_bias = (const float*)d_in[5];
  const float* in_vals  = (const float*)d_in[6];
  const int*   in_rows  = (const int*)d_in[7];
  const int*   in_cols  = (const int*)d_in[8];
  const float* in_bias  = (const float*)d_in[9];

  const int res_nnz = in_sizes[2];
  const int in_nnz  = in_sizes[6];

  char* ws = (char*)d_ws;
  float* srcT = (float*)(ws + OFF_SRCT);
  float* out = (float*)d_out;

  if (ws_size >= REQ_A) {
    int* rcur = (int*)(ws + OFF_RCUR);
    int* bcur = (int*)(ws + OFF_BCUR);
    float* z  = (float*)(ws + OFF_Z);
    uint2* e1 = (uint2*)(ws + OFF_E1);
    uint2* e2 = (uint2*)(ws + OFF_E2);

    // rcur + bcur are contiguous: one async memset.
    hipMemsetAsync(rcur, 0, 32768 + 1024, stream);
    transpose_kernel<<<512, 256, 0, stream>>>(state, x, srcT);

    pass1_bin<<<(res_nnz + CHUNK - 1) / CHUNK, 256, 0, stream>>>(
        res_vals, res_rows, res_cols, res_nnz, 0, e1, bcur);
    pass1_bin<<<(in_nnz + CHUNK - 1) / CHUNK, 256, 0, stream>>>(
        in_vals, in_rows, in_cols, in_nnz, N_RES, e1, bcur);

    pass2_sort<<<NBK * SB2, 256, 0, stream>>>(e1, bcur, e2, rcur);

    tail_zero<<<(N_RES * 64 + 255) / 256, 256, 0, stream>>>(e2, rcur);

    accum_csr<<<N_RES / 4, 256, 0, stream>>>(e2, rcur, srcT, z);

    finalize_csr<<<512, 256, 0, stream>>>(z, state, res_bias, in_bias, out);
  } else {
    float* z = (float*)(ws + OFF_RCUR);
    hipMemsetAsync(z, 0, N_RES * BATCH * sizeof(float), stream);
    transpose_kernel<<<512, 256, 0, stream>>>(state, x, srcT);
    spmm_atomic<<<(res_nnz + 255) / 256, 256, 0, stream>>>(
        res_vals, res_rows, res_cols, srcT, 0, z, res_nnz);
    spmm_atomic<<<(in_nnz + 255) / 256, 256, 0, stream>>>(
        in_vals, in_rows, in_cols, srcT, N_RES, z, in_nnz);
    // finalize via z layout [r][b]
    finalize_csr<<<512, 256, 0, stream>>>(z, state, res_bias, in_bias, out);
  }
}